// Round 12
// baseline (99.105 us; speedup 1.0000x reference)
//
#include <hip/hip_runtime.h>
#include <math.h>

#define H 128
#define NF 100000
#define NC 25000
#define TM 64

typedef _Float16 f16;
typedef f16 f16x8 __attribute__((ext_vector_type(8)));
typedef f16 f16x4 __attribute__((ext_vector_type(4)));
typedef float f32x4 __attribute__((ext_vector_type(4)));

#define MFMA16(a, b, c) __builtin_amdgcn_mfma_f32_16x16x32_f16((a), (b), (c), 0, 0, 0)

// ws: fragment-ordered f16 weights (each fragment = 64 lanes x 8 f16 = 1 KB contiguous)
//   F1 @ 0     : [nt=8][kk=8][lane=64][8]   W1^T, k<256   (kk 0..3 = xg half, 4..7 = xs half)
//   F2 @ 32768 : [nt=8][kk=4][lane=64][8]   W2^T
//   F3 @ 49152 : [nt=8][kk=4][lane=64][8]   W3^T
// fragment element: n = nt*16 + (lane&15), k = kk*32 + (lane>>4)*8 + j

__global__ void prep_w(const float* __restrict__ W1, const float* __restrict__ W2,
                       const float* __restrict__ W3, f16* __restrict__ ws)
{
    int i = blockIdx.x * 256 + threadIdx.x;   // 0..65535, grid exact
    if (i < 32768) {
        int j = i & 7, lane = (i >> 3) & 63, kk = (i >> 9) & 7, nt = i >> 12;
        int n = nt * 16 + (lane & 15);
        int k = kk * 32 + (lane >> 4) * 8 + j;
        ws[i] = (f16)W1[k * H + n];
    } else if (i < 49152) {
        int q = i - 32768;
        int j = q & 7, lane = (q >> 3) & 63, kk = (q >> 9) & 3, nt = q >> 11;
        int n = nt * 16 + (lane & 15);
        int k = kk * 32 + (lane >> 4) * 8 + j;
        ws[i] = (f16)W2[k * H + n];
    } else {
        int q = i - 49152;
        int j = q & 7, lane = (q >> 3) & 63, kk = (q >> 9) & 3, nt = q >> 11;
        int n = nt * 16 + (lane & 15);
        int k = kk * 32 + (lane >> 4) * 8 + j;
        ws[i] = (f16)W3[k * H + n];
    }
}

__device__ __forceinline__ float silu_f(float v) {
    return v / (1.0f + __expf(-v));
}

// convert 8 f32 to f16 fragment
__device__ __forceinline__ f16x8 cvt8(float4 v0, float4 v1) {
    f16x8 r;
    r[0] = (f16)v0.x; r[1] = (f16)v0.y; r[2] = (f16)v0.z; r[3] = (f16)v0.w;
    r[4] = (f16)v1.x; r[5] = (f16)v1.y; r[6] = (f16)v1.z; r[7] = (f16)v1.w;
    return r;
}

// Layer 1 fully in registers (per-lane direct A loads); LDS only for h1/h2.
// 3 barriers total.
__global__ __launch_bounds__(256, 4)
void fused_mlp_v12(const float* __restrict__ x,     // [2][25000][128]
                   const float* __restrict__ xsc,   // [2][100000][128]
                   const int*   __restrict__ f2c,   // [100000]
                   const float* __restrict__ dist,  // [100000]
                   const float* __restrict__ W1,    // [257][128] (row 256 used as f32)
                   const float* __restrict__ b1,
                   const float* __restrict__ b2,
                   const float* __restrict__ b3,
                   const f16*   __restrict__ ws,
                   float* __restrict__ out)         // [200000][128]
{
    __shared__ __align__(16) f16 sA[TM * H];         // 16 KB: h plane only

    const int t = threadIdx.x;
    const int l = t & 63, w = t >> 6;
    const int wRow = (w >> 1) * 32;                  // 0 or 32
    const int wnt  = (w & 1) * 4;                    // first n-tile (of 8) for this wave
    const int lr = l & 15, lg = l >> 4;
    const int R0 = blockIdx.x * TM;

    const f16* F1 = ws;
    const f16* F2 = ws + 32768;
    const f16* F3 = ws + 49152;

    // ---- this lane's two A-rows (per-row batch handling; NF%16==0 not needed here) ----
    const int row0 = R0 + wRow + lr;
    const int row1 = row0 + 16;
    const int bb0 = row0 >= NF, bb1 = row1 >= NF;
    const int ci0 = f2c[row0 - bb0 * NF];
    const int ci1 = f2c[row1 - bb1 * NF];
    const float* xg0 = x + (long long)(bb0 * NC + ci0) * H;
    const float* xg1 = x + (long long)(bb1 * NC + ci1) * H;
    const float* xs0 = xsc + (long long)row0 * H;
    const float* xs1 = xsc + (long long)row1 * H;

    // ---- acc init: b1 + d*W1[256]  (dist float4 never straddles: indices %4==0, NF%4==0) ----
    f32x4 acc[2][4];
    float dd[2][4];
    #pragma unroll
    for (int mt = 0; mt < 2; ++mt) {
        int r4 = R0 + wRow + mt * 16 + lg * 4;
        int bb = r4 >= NF;
        float4 dv = *(const float4*)(dist + (r4 - bb * NF));
        dd[mt][0] = dv.x; dd[mt][1] = dv.y; dd[mt][2] = dv.z; dd[mt][3] = dv.w;
    }
    #pragma unroll
    for (int nt = 0; nt < 4; ++nt) {
        int col = (wnt + nt) * 16 + lr;
        float bc = b1[col];
        float wc = W1[256 * H + col];
        #pragma unroll
        for (int mt = 0; mt < 2; ++mt)
            #pragma unroll
            for (int r = 0; r < 4; ++r)
                acc[mt][nt][r] = bc + dd[mt][r] * wc;
    }

    // ---- layer 1, xg half (W1 fragments kk=0..3), all from registers ----
    {
        #pragma unroll
        for (int kk = 0; kk < 4; ++kk) {
            const int kc = kk * 32 + (lg << 3);
            f16x8 a0 = cvt8(*(const float4*)(xg0 + kc), *(const float4*)(xg0 + kc + 4));
            f16x8 a1 = cvt8(*(const float4*)(xg1 + kc), *(const float4*)(xg1 + kc + 4));
            #pragma unroll
            for (int nt = 0; nt < 4; ++nt) {
                f16x8 wv = *(const f16x8*)(F1 + ((((wnt + nt) * 8 + kk) * 64 + l) << 3));
                acc[0][nt] = MFMA16(a0, wv, acc[0][nt]);
                acc[1][nt] = MFMA16(a1, wv, acc[1][nt]);
            }
        }
    }
    // ---- layer 1, xs half (W1 fragments kk=4..7) ----
    {
        #pragma unroll
        for (int kk = 0; kk < 4; ++kk) {
            const int kc = kk * 32 + (lg << 3);
            f16x8 a0 = cvt8(*(const float4*)(xs0 + kc), *(const float4*)(xs0 + kc + 4));
            f16x8 a1 = cvt8(*(const float4*)(xs1 + kc), *(const float4*)(xs1 + kc + 4));
            #pragma unroll
            for (int nt = 0; nt < 4; ++nt) {
                f16x8 wv = *(const f16x8*)(F1 + ((((wnt + nt) * 8 + kk + 4) * 64 + l) << 3));
                acc[0][nt] = MFMA16(a0, wv, acc[0][nt]);
                acc[1][nt] = MFMA16(a1, wv, acc[1][nt]);
            }
        }
    }

    // ---- h1 -> sA (swizzled f16) ----
    #pragma unroll
    for (int nt = 0; nt < 4; ++nt)
        #pragma unroll
        for (int mt = 0; mt < 2; ++mt)
            #pragma unroll
            for (int r = 0; r < 4; ++r) {
                int row = wRow + mt * 16 + lg * 4 + r;
                int col = (wnt + nt) * 16 + lr;
                sA[row * H + (((col >> 3) ^ (row & 7)) << 3) + (col & 7)] =
                    (f16)silu_f(acc[mt][nt][r]);
            }
    __syncthreads();                                 // B1: h1 ready

    // ---- layer 2 ----
    #pragma unroll
    for (int nt = 0; nt < 4; ++nt) {
        float bc = b2[(wnt + nt) * 16 + lr];
        #pragma unroll
        for (int mt = 0; mt < 2; ++mt)
            #pragma unroll
            for (int r = 0; r < 4; ++r)
                acc[mt][nt][r] = bc;
    }
    {
        #pragma unroll
        for (int kk = 0; kk < 4; ++kk) {
            int k = kk * 32 + (lg << 3);
            int slot = (((k >> 3) ^ (lr & 7)) << 3);
            f16x8 a0 = *(const f16x8*)(sA + (wRow + lr) * H + slot);
            f16x8 a1 = *(const f16x8*)(sA + (wRow + 16 + lr) * H + slot);
            #pragma unroll
            for (int nt = 0; nt < 4; ++nt) {
                f16x8 wv = *(const f16x8*)(F2 + ((((wnt + nt) * 4 + kk) * 64 + l) << 3));
                acc[0][nt] = MFMA16(a0, wv, acc[0][nt]);
                acc[1][nt] = MFMA16(a1, wv, acc[1][nt]);
            }
        }
    }
    __syncthreads();                                 // B2: h1 reads done

    // ---- h2 -> sA ----
    #pragma unroll
    for (int nt = 0; nt < 4; ++nt)
        #pragma unroll
        for (int mt = 0; mt < 2; ++mt)
            #pragma unroll
            for (int r = 0; r < 4; ++r) {
                int row = wRow + mt * 16 + lg * 4 + r;
                int col = (wnt + nt) * 16 + lr;
                sA[row * H + (((col >> 3) ^ (row & 7)) << 3) + (col & 7)] =
                    (f16)silu_f(acc[mt][nt][r]);
            }
    __syncthreads();                                 // B3: h2 ready

    // ---- layer 3 ----
    #pragma unroll
    for (int nt = 0; nt < 4; ++nt) {
        float bc = b3[(wnt + nt) * 16 + lr];
        #pragma unroll
        for (int mt = 0; mt < 2; ++mt)
            #pragma unroll
            for (int r = 0; r < 4; ++r)
                acc[mt][nt][r] = bc;
    }
    {
        #pragma unroll
        for (int kk = 0; kk < 4; ++kk) {
            int k = kk * 32 + (lg << 3);
            int slot = (((k >> 3) ^ (lr & 7)) << 3);
            f16x8 a0 = *(const f16x8*)(sA + (wRow + lr) * H + slot);
            f16x8 a1 = *(const f16x8*)(sA + (wRow + 16 + lr) * H + slot);
            #pragma unroll
            for (int nt = 0; nt < 4; ++nt) {
                f16x8 wv = *(const f16x8*)(F3 + ((((wnt + nt) * 4 + kk) * 64 + l) << 3));
                acc[0][nt] = MFMA16(a0, wv, acc[0][nt]);
                acc[1][nt] = MFMA16(a1, wv, acc[1][nt]);
            }
        }
    }

    // ---- store out ----
    #pragma unroll
    for (int mt = 0; mt < 2; ++mt)
        #pragma unroll
        for (int nt = 0; nt < 4; ++nt)
            #pragma unroll
            for (int r = 0; r < 4; ++r) {
                long long row = (long long)R0 + wRow + mt * 16 + lg * 4 + r;
                int col = (wnt + nt) * 16 + lr;
                out[row * H + col] = acc[mt][nt][r];
            }
}

extern "C" void kernel_launch(void* const* d_in, const int* in_sizes, int n_in,
                              void* d_out, int out_size, void* d_ws, size_t ws_size,
                              hipStream_t stream)
{
    const float* x    = (const float*)d_in[0];
    const float* xsc  = (const float*)d_in[1];
    const int*   f2c  = (const int*)d_in[2];
    const float* dist = (const float*)d_in[3];
    const float* W1   = (const float*)d_in[4];
    const float* b1   = (const float*)d_in[5];
    const float* W2   = (const float*)d_in[6];
    const float* b2   = (const float*)d_in[7];
    const float* W3   = (const float*)d_in[8];
    const float* b3   = (const float*)d_in[9];
    f16* ws = (f16*)d_ws;

    prep_w<<<256, 256, 0, stream>>>(W1, W2, W3, ws);

    const int n_rows = 2 * NF;                    // 200000
    dim3 grid(n_rows / TM);                       // 3125
    fused_mlp_v12<<<grid, 256, 0, stream>>>(x, xsc, f2c, dist, W1, b1, b2, b3,
                                            ws, (float*)d_out);
}